// Round 5
// baseline (600.504 us; speedup 1.0000x reference)
//
#include <hip/hip_runtime.h>
#include <hip/hip_bf16.h>
#include <math.h>

#define B_DIM 2048
#define L_DIM 2048
#define F_DIM 1024
#define H_DIM 4096
#define P_DIM 88

typedef unsigned short u16;
typedef short bf16x8 __attribute__((ext_vector_type(8)));
typedef float f32x4 __attribute__((ext_vector_type(4)));

// ---- bf16 split helpers (RNE) ----
__device__ __forceinline__ u16 f2bf(float x) {
    unsigned u = __float_as_uint(x);
    return (u16)((u + 0x7fffu + ((u >> 16) & 1u)) >> 16);
}
__device__ __forceinline__ float bf2f(u16 h) {
    return __uint_as_float(((unsigned)h) << 16);
}

// ---- async global->LDS, 16B per lane (dest = wave-uniform base + lane*16) ----
__device__ __forceinline__ void gload_lds16(const void* g, void* l) {
    unsigned loff = (unsigned)(uintptr_t)l;
    __builtin_amdgcn_global_load_lds(
        reinterpret_cast<const __attribute__((address_space(1))) void*>(
            reinterpret_cast<uintptr_t>(g)),
        reinterpret_cast<__attribute__((address_space(3))) void*>(loff),
        16, 0, 0);
}

// ---------------------------------------------------------------------------
// Fused start_fc + 2048-pt FFT per row -> A1 [xr_h | xr_l | xi_h | xi_l]
// Twiddles from an LDS table (1024 sincosf/block vs 11264; identical floats
// since j/2^s == (j<<(11-s))/2048 exactly).
// ---------------------------------------------------------------------------
__global__ __launch_bounds__(256) void fft_kernel(
    const float* __restrict__ x, const float* __restrict__ w_start,
    const float* __restrict__ b_start, u16* __restrict__ A1)
{
    __shared__ float re[2048];
    __shared__ float im[2048];
    __shared__ float twr[1024];
    __shared__ float twi[1024];
    int b = blockIdx.x;

    const float4* wp = (const float4*)w_start;
    float4 w0 = wp[0], w1 = wp[1], w2 = wp[2], w3 = wp[3];
    float bs = b_start[0];

    for (int i = threadIdx.x; i < 1024; i += 256) {
        float ang = -6.283185307179586f * ((float)i / 2048.0f);
        sincosf(ang, &twi[i], &twr[i]);
    }

    for (int l = threadIdx.x; l < 2048; l += 256) {
        const float4* xp = (const float4*)(x + ((size_t)b * 2048 + l) * 16);
        float4 x0 = xp[0], x1 = xp[1], x2 = xp[2], x3 = xp[3];
        float acc = bs;
        acc += x0.x * w0.x + x0.y * w0.y + x0.z * w0.z + x0.w * w0.w;
        acc += x1.x * w1.x + x1.y * w1.y + x1.z * w1.z + x1.w * w1.w;
        acc += x2.x * w2.x + x2.y * w2.y + x2.z * w2.z + x2.w * w2.w;
        acc += x3.x * w3.x + x3.y * w3.y + x3.z * w3.z + x3.w * w3.w;
        unsigned j = __brev((unsigned)l) >> 21;   // bit-reversed position
        re[j] = acc;
        im[j] = 0.f;
    }
    __syncthreads();

    for (int s = 1; s <= 11; s++) {
        int half = 1 << (s - 1);
        for (int t = threadIdx.x; t < 1024; t += 256) {
            int j = t & (half - 1);
            int base = (t >> (s - 1)) << s;
            int idx = j << (11 - s);
            float wr = twr[idx], wi = twi[idx];
            int i0 = base + j, i1 = i0 + half;
            float br = re[i1], bi = im[i1];
            float tr = br * wr - bi * wi;
            float ti = br * wi + bi * wr;
            float ar = re[i0], ai = im[i0];
            re[i0] = ar + tr; im[i0] = ai + ti;
            re[i1] = ar - tr; im[i1] = ai - ti;
        }
        __syncthreads();
    }

    const float sc = 0.022097086912079612f;  // 1/sqrt(2048)
    u16* arow = A1 + (size_t)b * 4096;
    for (int t = threadIdx.x; t < 1024; t += 256) {
        float r = re[t + 1] * sc;
        float q = im[t + 1] * sc;
        u16 rh = f2bf(r); u16 rl = f2bf(r - bf2f(rh));
        u16 ih = f2bf(q); u16 il = f2bf(q - bf2f(ih));
        arow[t] = rh; arow[1024 + t] = rl;
        arow[2048 + t] = ih; arow[3072 + t] = il;
    }
}

// ---------------------------------------------------------------------------
// Weight conversion w[2][Kc][Nh] fp32 -> BT [2*Nh][4*Kc] bf16 (transposed, split)
// ---------------------------------------------------------------------------
__global__ __launch_bounds__(256) void conv_bt_kernel(
    const float* __restrict__ w, u16* __restrict__ BT, int Kc, int Nh)
{
    __shared__ float t0[32][33];
    __shared__ float t1[32][33];
    int k0 = blockIdx.x * 32, n0 = blockIdx.y * 32;
    int tx = threadIdx.x, ty = threadIdx.y;     // (32, 8)
    const float* w0 = w;
    const float* w1 = w + (size_t)Kc * Nh;

#pragma unroll
    for (int i = 0; i < 4; i++) {
        int k = k0 + ty + 8 * i;
        t0[ty + 8 * i][tx] = w0[(size_t)k * Nh + n0 + tx];
        t1[ty + 8 * i][tx] = w1[(size_t)k * Nh + n0 + tx];
    }
    __syncthreads();

    size_t K4 = 4 * (size_t)Kc;
    int k = k0 + tx;
#pragma unroll
    for (int i = 0; i < 4; i++) {
        int nl = ty + 8 * i;
        int n = n0 + nl;
        float br = t0[tx][nl];
        float bi = t1[tx][nl];
        u16 brh = f2bf(br); u16 brl = f2bf(br - bf2f(brh));
        float nbi = -bi;
        u16 nih = f2bf(nbi); u16 nil = f2bf(nbi - bf2f(nih));
        u16 pih = f2bf(bi);  u16 pil = f2bf(bi - bf2f(pih));
        u16* rowr = BT + (size_t)n * K4;
        rowr[0 * Kc + k] = brh; rowr[1 * Kc + k] = brl;
        rowr[2 * Kc + k] = nih; rowr[3 * Kc + k] = nil;
        u16* rowi = BT + (size_t)(Nh + n) * K4;
        rowi[0 * Kc + k] = pih; rowi[1 * Kc + k] = pil;
        rowi[2 * Kc + k] = brh; rowi[3 * Kc + k] = brl;
    }
}

// ---------------------------------------------------------------------------
// Split-bf16 GEMM, m201-style 4-phase/K64 schedule with counted vmcnt.
// 256x256 tile, BK=64 (2 k-halves), 8 waves (2M x 4N), dbuf 2 slots.
// LDS slot (64 KB): [khalf][A 256x32 | B 256x32] bf16, row = 64 B,
// chunk swizzle c' = c ^ ((row>>1)&3) (pre-swizzled global source).
// Per tile: P0{read A-M0,B k0; stage k0(t+1); 16 MFMA}
//           P1{read A-M1 k0; 16 MFMA; vmcnt(4|0); barrier}
//           P2{read A-M0,B k1; stage k1(t+1); 16 MFMA}
//           P3{read A-M1 k1; 16 MFMA; vmcnt(4|-); barrier}
// In-flight never drains below 4 loads (1 k-half) in steady state.
// ---------------------------------------------------------------------------
extern __shared__ char smem8p[];

#define MFMA_PHASE(MB, A0_, A1_, A2_, A3_, B0_, B1_, B2_, B3_)                        \
    acc[MB+0][0] = __builtin_amdgcn_mfma_f32_16x16x32_bf16(A0_, B0_, acc[MB+0][0],0,0,0); \
    acc[MB+0][1] = __builtin_amdgcn_mfma_f32_16x16x32_bf16(A0_, B1_, acc[MB+0][1],0,0,0); \
    acc[MB+0][2] = __builtin_amdgcn_mfma_f32_16x16x32_bf16(A0_, B2_, acc[MB+0][2],0,0,0); \
    acc[MB+0][3] = __builtin_amdgcn_mfma_f32_16x16x32_bf16(A0_, B3_, acc[MB+0][3],0,0,0); \
    acc[MB+1][0] = __builtin_amdgcn_mfma_f32_16x16x32_bf16(A1_, B0_, acc[MB+1][0],0,0,0); \
    acc[MB+1][1] = __builtin_amdgcn_mfma_f32_16x16x32_bf16(A1_, B1_, acc[MB+1][1],0,0,0); \
    acc[MB+1][2] = __builtin_amdgcn_mfma_f32_16x16x32_bf16(A1_, B2_, acc[MB+1][2],0,0,0); \
    acc[MB+1][3] = __builtin_amdgcn_mfma_f32_16x16x32_bf16(A1_, B3_, acc[MB+1][3],0,0,0); \
    acc[MB+2][0] = __builtin_amdgcn_mfma_f32_16x16x32_bf16(A2_, B0_, acc[MB+2][0],0,0,0); \
    acc[MB+2][1] = __builtin_amdgcn_mfma_f32_16x16x32_bf16(A2_, B1_, acc[MB+2][1],0,0,0); \
    acc[MB+2][2] = __builtin_amdgcn_mfma_f32_16x16x32_bf16(A2_, B2_, acc[MB+2][2],0,0,0); \
    acc[MB+2][3] = __builtin_amdgcn_mfma_f32_16x16x32_bf16(A2_, B3_, acc[MB+2][3],0,0,0); \
    acc[MB+3][0] = __builtin_amdgcn_mfma_f32_16x16x32_bf16(A3_, B0_, acc[MB+3][0],0,0,0); \
    acc[MB+3][1] = __builtin_amdgcn_mfma_f32_16x16x32_bf16(A3_, B1_, acc[MB+3][1],0,0,0); \
    acc[MB+3][2] = __builtin_amdgcn_mfma_f32_16x16x32_bf16(A3_, B2_, acc[MB+3][2],0,0,0); \
    acc[MB+3][3] = __builtin_amdgcn_mfma_f32_16x16x32_bf16(A3_, B3_, acc[MB+3][3],0,0,0);

template <int EPI, int SWZ>
__global__ __launch_bounds__(512, 2) void gemm8p(
    const u16* __restrict__ A, const u16* __restrict__ B,
    const float* __restrict__ biasL, const float* __restrict__ biasR,
    u16* __restrict__ OutU, float* __restrict__ P01, float* __restrict__ P23,
    int Kc, int KcLog, int NH, int nt)
{
    const int tid = threadIdx.x;
    const int w = tid >> 6, lane = tid & 63;
    const int wr = w >> 2, wc = w & 3;           // 2M x 4N waves
    const int fr = lane & 15, kb = lane >> 4;

    int bx, by, z;
    if (SWZ) {
        int b = blockIdx.x;
        int xcd = b & 7, idx = b >> 3;
        bx = 4 * xcd + (idx & 3);                // 32 N-blocks
        by = idx >> 2;                           // 8 M-blocks
        z = 0;
    } else {
        bx = blockIdx.x; by = blockIdx.y; z = blockIdx.z;
    }
    const int n0 = bx * 256, m0 = by * 256;
    const size_t K4 = 4 * (size_t)Kc;

    // ---- staging setup: per k-half = 4 gloads/thread (2 A + 2 B) ----
    const int srow = lane >> 2;                  // 0..15
    const int pch  = lane & 3;                   // phys 16B chunk in 64B row
    const int rU0 = w * 32 + srow;               // unit-0 row (0..255)
    const int rU1 = rU0 + 16;
    const int e0 = (pch ^ ((rU0 >> 1) & 3)) * 8; // pre-swizzled src elem offset
    const int e1 = (pch ^ ((rU1 >> 1) & 3)) * 8;
    const u16* gA0 = A + (size_t)(m0 + rU0) * K4 + e0;
    const u16* gA1 = A + (size_t)(m0 + rU1) * K4 + e1;
    const u16* gB0 = B + (size_t)(n0 + rU0) * K4 + e0;
    const u16* gB1 = B + (size_t)(n0 + rU1) * K4 + e1;
    const int dU0 = (w * 32) * 64;               // wave-uniform LDS dests
    const int dU1 = dU0 + 16 * 64;

    // ---- frag-read setup ----
    const int xk   = (kb ^ ((fr >> 1) & 3)) << 4;
    const int aOff = (wr * 128 + fr) * 64 + xk;
    const int bOff = 16384 + (wc * 64 + fr) * 64 + xk;

    f32x4 acc[8][4];
#pragma unroll
    for (int i = 0; i < 8; i++)
#pragma unroll
        for (int j = 0; j < 4; j++)
            acc[i][j] = (f32x4){0.f, 0.f, 0.f, 0.f};

    auto colA = [&](int t) {
        int k0 = t << 6;
        int seg = k0 >> KcLog, kk = k0 & (Kc - 1);
        int r3 = seg >= 3 ? seg - 3 : seg;
        int bs = seg >= 3 ? 2 : 0;
        return (bs + (r3 == 1 ? 1 : 0)) * Kc + kk;
    };
    auto colB = [&](int t) {
        int k0 = t << 6;
        int seg = k0 >> KcLog, kk = k0 & (Kc - 1);
        int r3 = seg >= 3 ? seg - 3 : seg;
        int bs = seg >= 3 ? 2 : 0;
        return (bs + (r3 == 2 ? 1 : 0)) * Kc + kk;
    };
    auto stageK = [&](int t, int ks) {
        char* d = smem8p + ((t & 1) << 16) + (ks << 15);
        int cA = colA(t) + ks * 32;
        int cB = colB(t) + ks * 32;
        gload_lds16(gA0 + cA, d + dU0);
        gload_lds16(gA1 + cA, d + dU1);
        gload_lds16(gB0 + cB, d + 16384 + dU0);
        gload_lds16(gB1 + cB, d + 16384 + dU1);
    };

    const int t0 = z * nt, te = t0 + nt;

    // prologue: both k-halves of t0; confirm k0(t0); publish
    stageK(t0, 0);
    stageK(t0, 1);
    asm volatile("s_waitcnt vmcnt(4)" ::: "memory");
    asm volatile("s_barrier" ::: "memory");

    for (int t = t0; t < te; ++t) {
        const char* sl = smem8p + ((t & 1) << 16);
        const char* aP = sl + aOff;
        const char* bP = sl + bOff;
        const bool more = (t + 1 < te);

        // ---- P0: (M-half 0, k-half 0) ----
        bf16x8 a0 = *(const bf16x8*)(aP + 0 * 1024);
        bf16x8 a1 = *(const bf16x8*)(aP + 1 * 1024);
        bf16x8 a2 = *(const bf16x8*)(aP + 2 * 1024);
        bf16x8 a3 = *(const bf16x8*)(aP + 3 * 1024);
        bf16x8 b0 = *(const bf16x8*)(bP + 0 * 1024);
        bf16x8 b1 = *(const bf16x8*)(bP + 1 * 1024);
        bf16x8 b2 = *(const bf16x8*)(bP + 2 * 1024);
        bf16x8 b3 = *(const bf16x8*)(bP + 3 * 1024);
        if (more) stageK(t + 1, 0);
        __builtin_amdgcn_s_setprio(1);
        MFMA_PHASE(0, a0, a1, a2, a3, b0, b1, b2, b3)
        __builtin_amdgcn_s_setprio(0);

        // ---- P1: (M-half 1, k-half 0) ----
        a0 = *(const bf16x8*)(aP + 4 * 1024);
        a1 = *(const bf16x8*)(aP + 5 * 1024);
        a2 = *(const bf16x8*)(aP + 6 * 1024);
        a3 = *(const bf16x8*)(aP + 7 * 1024);
        __builtin_amdgcn_s_setprio(1);
        MFMA_PHASE(4, a0, a1, a2, a3, b0, b1, b2, b3)
        __builtin_amdgcn_s_setprio(0);
        // confirm k1(t) (allow {k0(t+1)} to stay in flight)
        if (more) asm volatile("s_waitcnt vmcnt(4)" ::: "memory");
        else      asm volatile("s_waitcnt vmcnt(0)" ::: "memory");
        asm volatile("s_barrier" ::: "memory");

        // ---- P2: (M-half 0, k-half 1) ----
        const char* aQ = aP + 32768;
        const char* bQ = bP + 32768;
        a0 = *(const bf16x8*)(aQ + 0 * 1024);
        a1 = *(const bf16x8*)(aQ + 1 * 1024);
        a2 = *(const bf16x8*)(aQ + 2 * 1024);
        a3 = *(const bf16x8*)(aQ + 3 * 1024);
        b0 = *(const bf16x8*)(bQ + 0 * 1024);
        b1 = *(const bf16x8*)(bQ + 1 * 1024);
        b2 = *(const bf16x8*)(bQ + 2 * 1024);
        b3 = *(const bf16x8*)(bQ + 3 * 1024);
        if (more) stageK(t + 1, 1);
        __builtin_amdgcn_s_setprio(1);
        MFMA_PHASE(0, a0, a1, a2, a3, b0, b1, b2, b3)
        __builtin_amdgcn_s_setprio(0);

        // ---- P3: (M-half 1, k-half 1) ----
        a0 = *(const bf16x8*)(aQ + 4 * 1024);
        a1 = *(const bf16x8*)(aQ + 5 * 1024);
        a2 = *(const bf16x8*)(aQ + 6 * 1024);
        a3 = *(const bf16x8*)(aQ + 7 * 1024);
        __builtin_amdgcn_s_setprio(1);
        MFMA_PHASE(4, a0, a1, a2, a3, b0, b1, b2, b3)
        __builtin_amdgcn_s_setprio(0);
        // confirm k0(t+1) (allow {k1(t+1)} to stay in flight)
        if (more) asm volatile("s_waitcnt vmcnt(4)" ::: "memory");
        asm volatile("s_barrier" ::: "memory");
    }

    // ---- epilogue ----
    const int fq = kb;
#pragma unroll
    for (int nj = 0; nj < 4; nj++) {
        int n = n0 + wc * 64 + nj * 16 + fr;
        if (EPI == 0) {
            bool left = (n < NH);
            int nn = left ? n : (n - NH);
            float bias = left ? biasL[n] : biasR[nn];
#pragma unroll
            for (int mi = 0; mi < 8; mi++) {
                int mb = m0 + wr * 128 + mi * 16 + fq * 4;
#pragma unroll
                for (int r = 0; r < 4; r++) {
                    float val = fmaxf(acc[mi][nj][r] + bias, 0.f);
                    u16 h = f2bf(val);
                    u16 lo = f2bf(val - bf2f(h));
                    size_t rb = (size_t)(mb + r) * (4 * (size_t)NH);
                    if (left) { OutU[rb + nn] = h; OutU[rb + NH + nn] = lo; }
                    else { OutU[rb + 2 * (size_t)NH + nn] = h; OutU[rb + 3 * (size_t)NH + nn] = lo; }
                }
            }
        } else {
            const size_t PSZ = (size_t)2048 * 2048;
            float* Out = (z < 2) ? (P01 + (size_t)z * PSZ) : (P23 + (size_t)(z - 2) * PSZ);
#pragma unroll
            for (int mi = 0; mi < 8; mi++) {
                int mb = m0 + wr * 128 + mi * 16 + fq * 4;
#pragma unroll
                for (int r = 0; r < 4; r++)
                    Out[(size_t)(mb + r) * 2048 + n] = acc[mi][nj][r];
            }
        }
    }
}

// ---------------------------------------------------------------------------
// Router: sum split-K partials + bias -> amp -> logits -> top-3 -> gates
// ---------------------------------------------------------------------------
__global__ __launch_bounds__(128) void router_kernel(
    const float* __restrict__ P01, const float* __restrict__ P23, int ZK,
    const float* __restrict__ b2,
    const float* __restrict__ w_gate, const float* __restrict__ w_noise,
    const float* __restrict__ noise_z, float* __restrict__ gates)
{
    __shared__ float s_amp[1024];
    __shared__ float s_logit[P_DIM];
    __shared__ int   s_idx[3];
    __shared__ float s_val[3];

    int b = blockIdx.x;
    const size_t PSZ = (size_t)2048 * 2048;
    const size_t roff = (size_t)b * 2048;

    for (int i = threadIdx.x; i < 1024; i += 128) {
        float orr = b2[i];
        float oii = b2[1024 + i];
        for (int zz = 0; zz < ZK; zz++) {
            const float* Pz = ((zz < 2) ? (P01 + (size_t)zz * PSZ)
                                        : (P23 + (size_t)(zz - 2) * PSZ)) + roff;
            orr += Pz[i];
            oii += Pz[1024 + i];
        }
        s_amp[i] = sqrtf(orr * orr + oii * oii);
    }
    __syncthreads();

    int p = threadIdx.x;
    if (p < P_DIM) {
        float cg = 0.f, cn = 0.f;
        for (int k = 0; k < 1024; k++) {
            float a = s_amp[k];
            cg = fmaf(a, w_gate[k * P_DIM + p], cg);
            cn = fmaf(a, w_noise[k * P_DIM + p], cn);
        }
        float ns = (cn > 20.f) ? cn : log1pf(expf(cn));
        ns += 0.01f;
        s_logit[p] = cg + noise_z[(size_t)b * P_DIM + p] * ns;
    }
    __syncthreads();

    if (threadIdx.x == 0) {
        int i0 = -1, i1 = -1, i2 = -1;
        float v0 = -1e30f, v1 = -1e30f, v2 = -1e30f;
        for (int i = 0; i < P_DIM; i++) {
            float t = s_logit[i];
            if (t > v0) { v0 = t; i0 = i; }
        }
        for (int i = 0; i < P_DIM; i++) {
            if (i == i0) continue;
            float t = s_logit[i];
            if (t > v1) { v1 = t; i1 = i; }
        }
        for (int i = 0; i < P_DIM; i++) {
            if (i == i0 || i == i1) continue;
            float t = s_logit[i];
            if (t > v2) { v2 = t; i2 = i; }
        }
        s_idx[0] = i0; s_idx[1] = i1; s_idx[2] = i2;
        s_val[0] = v0; s_val[1] = v1; s_val[2] = v2;
    }
    __syncthreads();

    if (p < P_DIM) {
        float m = s_val[0];
        float e0 = expf(s_val[0] - m);
        float e1 = expf(s_val[1] - m);
        float e2 = expf(s_val[2] - m);
        float inv = 1.f / (e0 + e1 + e2);
        float g = 0.f;
        if (p == s_idx[0]) g = e0 * inv;
        else if (p == s_idx[1]) g = e1 * inv;
        else if (p == s_idx[2]) g = e2 * inv;
        gates[(size_t)b * P_DIM + p] = g;
    }
}

// ---------------------------------------------------------------------------
extern "C" void kernel_launch(void* const* d_in, const int* in_sizes, int n_in,
                              void* d_out, int out_size, void* d_ws, size_t ws_size,
                              hipStream_t stream)
{
    const float* x       = (const float*)d_in[0];
    const float* w_start = (const float*)d_in[1];
    const float* b_start = (const float*)d_in[2];
    const float* w1      = (const float*)d_in[3];
    const float* b1      = (const float*)d_in[4];
    const float* w2      = (const float*)d_in[5];
    const float* b2      = (const float*)d_in[6];
    const float* w_gate  = (const float*)d_in[7];
    const float* w_noise = (const float*)d_in[8];
    const float* noise_z = (const float*)d_in[9];
    float* gates = (float*)d_out;

    const size_t MB = 1024 * 1024;
    char* base = (char*)d_ws;
    u16*  A1   = (u16*)(base + 16 * MB);     // [16,32) — dead after gemm1
    u16*  BT   = (u16*)(base + 32 * MB);     // [32,96) — BT1 then BT2
    u16*  A2   = (u16*)(base + 96 * MB);     // [96,160)
    float* P01 = (float*)base;               // partials z0,z1 -> [0,32)
    float* P23 = (float*)(base + 160 * MB);  // partials z2,z3 -> [160,192)

    int ZK = (ws_size >= (size_t)192 * MB) ? 4 : 2;

    hipFuncSetAttribute(reinterpret_cast<const void*>(&gemm8p<0, 1>),
                        hipFuncAttributeMaxDynamicSharedMemorySize, 131072);
    hipFuncSetAttribute(reinterpret_cast<const void*>(&gemm8p<1, 0>),
                        hipFuncAttributeMaxDynamicSharedMemorySize, 131072);

    fft_kernel<<<B_DIM, 256, 0, stream>>>(x, w_start, b_start, A1);

    // layer 1: M=2048, N=8192, Kc=1024 (K_eff=6144 -> 96 K64-tiles); XCD swizzle
    conv_bt_kernel<<<dim3(F_DIM / 32, H_DIM / 32), dim3(32, 8), 0, stream>>>(
        w1, BT, F_DIM, H_DIM);
    gemm8p<0, 1><<<256, 512, 131072, stream>>>(
        A1, BT, b1, b1 + H_DIM, A2, nullptr, nullptr, F_DIM, 10, H_DIM, 96);

    // layer 2: M=2048, N=2048, Kc=4096 (K_eff=24576 -> 384 K64-tiles), split-K
    conv_bt_kernel<<<dim3(H_DIM / 32, F_DIM / 32), dim3(32, 8), 0, stream>>>(
        w2, BT, H_DIM, F_DIM);
    gemm8p<1, 0><<<dim3(8, 8, ZK), 512, 131072, stream>>>(
        A2, BT, nullptr, nullptr, nullptr, P01, P23, H_DIM, 12, F_DIM, 384 / ZK);

    router_kernel<<<B_DIM, 128, 0, stream>>>(
        P01, P23, ZK, b2, w_gate, w_noise, noise_z, gates);
}

// Round 6
// 598.326 us; speedup vs baseline: 1.0036x; 1.0036x over previous
//
#include <hip/hip_runtime.h>
#include <hip/hip_bf16.h>
#include <math.h>

#define B_DIM 2048
#define L_DIM 2048
#define F_DIM 1024
#define H_DIM 4096
#define P_DIM 88

typedef unsigned short u16;
typedef short bf16x8 __attribute__((ext_vector_type(8)));
typedef float f32x4 __attribute__((ext_vector_type(4)));

// ---- bf16 split helpers (RNE) ----
__device__ __forceinline__ u16 f2bf(float x) {
    unsigned u = __float_as_uint(x);
    return (u16)((u + 0x7fffu + ((u >> 16) & 1u)) >> 16);
}
__device__ __forceinline__ float bf2f(u16 h) {
    return __uint_as_float(((unsigned)h) << 16);
}

// ---- async global->LDS, 16B per lane (dest = wave-uniform base + lane*16) ----
__device__ __forceinline__ void gload_lds16(const void* g, void* l) {
    unsigned loff = (unsigned)(uintptr_t)l;
    __builtin_amdgcn_global_load_lds(
        reinterpret_cast<const __attribute__((address_space(1))) void*>(
            reinterpret_cast<uintptr_t>(g)),
        reinterpret_cast<__attribute__((address_space(3))) void*>(loff),
        16, 0, 0);
}

// ---------------------------------------------------------------------------
// Fused start_fc + 2048-pt FFT per row -> A1 [xr_h | xr_l | xi_h | xi_l]
// Twiddles from an LDS table (identical floats: j/2^s == (j<<(11-s))/2048).
// ---------------------------------------------------------------------------
__global__ __launch_bounds__(256) void fft_kernel(
    const float* __restrict__ x, const float* __restrict__ w_start,
    const float* __restrict__ b_start, u16* __restrict__ A1)
{
    __shared__ float re[2048];
    __shared__ float im[2048];
    __shared__ float twr[1024];
    __shared__ float twi[1024];
    int b = blockIdx.x;

    const float4* wp = (const float4*)w_start;
    float4 w0 = wp[0], w1 = wp[1], w2 = wp[2], w3 = wp[3];
    float bs = b_start[0];

    for (int i = threadIdx.x; i < 1024; i += 256) {
        float ang = -6.283185307179586f * ((float)i / 2048.0f);
        sincosf(ang, &twi[i], &twr[i]);
    }

    for (int l = threadIdx.x; l < 2048; l += 256) {
        const float4* xp = (const float4*)(x + ((size_t)b * 2048 + l) * 16);
        float4 x0 = xp[0], x1 = xp[1], x2 = xp[2], x3 = xp[3];
        float acc = bs;
        acc += x0.x * w0.x + x0.y * w0.y + x0.z * w0.z + x0.w * w0.w;
        acc += x1.x * w1.x + x1.y * w1.y + x1.z * w1.z + x1.w * w1.w;
        acc += x2.x * w2.x + x2.y * w2.y + x2.z * w2.z + x2.w * w2.w;
        acc += x3.x * w3.x + x3.y * w3.y + x3.z * w3.z + x3.w * w3.w;
        unsigned j = __brev((unsigned)l) >> 21;   // bit-reversed position
        re[j] = acc;
        im[j] = 0.f;
    }
    __syncthreads();

    for (int s = 1; s <= 11; s++) {
        int half = 1 << (s - 1);
        for (int t = threadIdx.x; t < 1024; t += 256) {
            int j = t & (half - 1);
            int base = (t >> (s - 1)) << s;
            int idx = j << (11 - s);
            float wr = twr[idx], wi = twi[idx];
            int i0 = base + j, i1 = i0 + half;
            float br = re[i1], bi = im[i1];
            float tr = br * wr - bi * wi;
            float ti = br * wi + bi * wr;
            float ar = re[i0], ai = im[i0];
            re[i0] = ar + tr; im[i0] = ai + ti;
            re[i1] = ar - tr; im[i1] = ai - ti;
        }
        __syncthreads();
    }

    const float sc = 0.022097086912079612f;  // 1/sqrt(2048)
    u16* arow = A1 + (size_t)b * 4096;
    for (int t = threadIdx.x; t < 1024; t += 256) {
        float r = re[t + 1] * sc;
        float q = im[t + 1] * sc;
        u16 rh = f2bf(r); u16 rl = f2bf(r - bf2f(rh));
        u16 ih = f2bf(q); u16 il = f2bf(q - bf2f(ih));
        arow[t] = rh; arow[1024 + t] = rl;
        arow[2048 + t] = ih; arow[3072 + t] = il;
    }
}

// ---------------------------------------------------------------------------
// Weight conversion w[2][Kc][Nh] fp32 -> BT [2*Nh][4*Kc] bf16 (transposed, split)
// ---------------------------------------------------------------------------
__global__ __launch_bounds__(256) void conv_bt_kernel(
    const float* __restrict__ w, u16* __restrict__ BT, int Kc, int Nh)
{
    __shared__ float t0[32][33];
    __shared__ float t1[32][33];
    int k0 = blockIdx.x * 32, n0 = blockIdx.y * 32;
    int tx = threadIdx.x, ty = threadIdx.y;     // (32, 8)
    const float* w0 = w;
    const float* w1 = w + (size_t)Kc * Nh;

#pragma unroll
    for (int i = 0; i < 4; i++) {
        int k = k0 + ty + 8 * i;
        t0[ty + 8 * i][tx] = w0[(size_t)k * Nh + n0 + tx];
        t1[ty + 8 * i][tx] = w1[(size_t)k * Nh + n0 + tx];
    }
    __syncthreads();

    size_t K4 = 4 * (size_t)Kc;
    int k = k0 + tx;
#pragma unroll
    for (int i = 0; i < 4; i++) {
        int nl = ty + 8 * i;
        int n = n0 + nl;
        float br = t0[tx][nl];
        float bi = t1[tx][nl];
        u16 brh = f2bf(br); u16 brl = f2bf(br - bf2f(brh));
        float nbi = -bi;
        u16 nih = f2bf(nbi); u16 nil = f2bf(nbi - bf2f(nih));
        u16 pih = f2bf(bi);  u16 pil = f2bf(bi - bf2f(pih));
        u16* rowr = BT + (size_t)n * K4;
        rowr[0 * Kc + k] = brh; rowr[1 * Kc + k] = brl;
        rowr[2 * Kc + k] = nih; rowr[3 * Kc + k] = nil;
        u16* rowi = BT + (size_t)(Nh + n) * K4;
        rowi[0 * Kc + k] = pih; rowi[1 * Kc + k] = pil;
        rowi[2 * Kc + k] = brh; rowi[3 * Kc + k] = brl;
    }
}

// ---------------------------------------------------------------------------
// Deep-pipelined split-bf16 GEMM (R4 ring-4/BK=32 structure + covered reads).
// 256x256 tile, BK=32, 8 waves (2M x 4N), ring of 4 LDS slots per operand.
// Per tile t:
//   stage(t+2); read ph2-A frags (slot t);      MFMA ph1 (a,b from last iter)
//   vmcnt(4 | 0 if no stage); s_barrier
//   read next-tile ph1-A frags (slot t+1);      MFMA ph2 (c,b)
//   read next-tile B frags (slot t+1)           [b regs free after ph2]
// Every ds_read batch has >=16 MFMA between issue and first use.
// Swizzle: chunk ^= (row>>1)&3 via pre-swizzled global source (0 conflicts).
// ---------------------------------------------------------------------------
extern __shared__ char smem8p[];

#define MFMA16(ACC0, ACC1, ACC2, ACC3, A0, A1, A2, A3, B0, B1, B2, B3)           \
    ACC0[0] = __builtin_amdgcn_mfma_f32_16x16x32_bf16(A0, B0, ACC0[0], 0, 0, 0); \
    ACC0[1] = __builtin_amdgcn_mfma_f32_16x16x32_bf16(A0, B1, ACC0[1], 0, 0, 0); \
    ACC0[2] = __builtin_amdgcn_mfma_f32_16x16x32_bf16(A0, B2, ACC0[2], 0, 0, 0); \
    ACC0[3] = __builtin_amdgcn_mfma_f32_16x16x32_bf16(A0, B3, ACC0[3], 0, 0, 0); \
    ACC1[0] = __builtin_amdgcn_mfma_f32_16x16x32_bf16(A1, B0, ACC1[0], 0, 0, 0); \
    ACC1[1] = __builtin_amdgcn_mfma_f32_16x16x32_bf16(A1, B1, ACC1[1], 0, 0, 0); \
    ACC1[2] = __builtin_amdgcn_mfma_f32_16x16x32_bf16(A1, B2, ACC1[2], 0, 0, 0); \
    ACC1[3] = __builtin_amdgcn_mfma_f32_16x16x32_bf16(A1, B3, ACC1[3], 0, 0, 0); \
    ACC2[0] = __builtin_amdgcn_mfma_f32_16x16x32_bf16(A2, B0, ACC2[0], 0, 0, 0); \
    ACC2[1] = __builtin_amdgcn_mfma_f32_16x16x32_bf16(A2, B1, ACC2[1], 0, 0, 0); \
    ACC2[2] = __builtin_amdgcn_mfma_f32_16x16x32_bf16(A2, B2, ACC2[2], 0, 0, 0); \
    ACC2[3] = __builtin_amdgcn_mfma_f32_16x16x32_bf16(A2, B3, ACC2[3], 0, 0, 0); \
    ACC3[0] = __builtin_amdgcn_mfma_f32_16x16x32_bf16(A3, B0, ACC3[0], 0, 0, 0); \
    ACC3[1] = __builtin_amdgcn_mfma_f32_16x16x32_bf16(A3, B1, ACC3[1], 0, 0, 0); \
    ACC3[2] = __builtin_amdgcn_mfma_f32_16x16x32_bf16(A3, B2, ACC3[2], 0, 0, 0); \
    ACC3[3] = __builtin_amdgcn_mfma_f32_16x16x32_bf16(A3, B3, ACC3[3], 0, 0, 0);

template <int EPI, int SWZ>
__global__ __launch_bounds__(512, 2) void gemm8p(
    const u16* __restrict__ A, const u16* __restrict__ B,
    const float* __restrict__ biasL, const float* __restrict__ biasR,
    u16* __restrict__ OutU, float* __restrict__ P01, float* __restrict__ P23,
    int Kc, int KcLog, int NH, int nt)
{
    char* ldsA = smem8p;              // 4 slots x 16384 B  (A tile 256x32 bf16)
    char* ldsB = smem8p + 65536;      // 4 slots x 16384 B

    const int tid = threadIdx.x;
    const int w = tid >> 6, lane = tid & 63;
    const int wr = w >> 2, wc = w & 3;           // 2M x 4N waves
    const int fr = lane & 15, kb = lane >> 4;

    int bx, by, z;
    if (SWZ) {
        int b = blockIdx.x;
        int xcd = b & 7, idx = b >> 3;
        bx = 4 * xcd + (idx & 3);                // 32 N-blocks
        by = idx >> 2;                           // 8 M-blocks
        z = 0;
    } else {
        bx = blockIdx.x; by = blockIdx.y; z = blockIdx.z;
    }
    const int n0 = bx * 256, m0 = by * 256;
    const size_t K4 = 4 * (size_t)Kc;

    // staging: thread covers one 16B chunk per issue; 2 issues each for A,B
    const int srow = tid >> 2;
    const int lk8 = (((tid & 3) ^ ((tid >> 3) & 3))) * 8;   // src elem offset
    const int wb = (tid >> 6) * 1024;                       // wave dest base (B)

    // frag read lane offset (bytes): row fr, chunk kb ^ ((fr>>1)&3)
    const int laneOff = fr * 64 + ((kb ^ ((fr >> 1) & 3)) << 4);

    f32x4 acc[8][4];
#pragma unroll
    for (int i = 0; i < 8; i++)
#pragma unroll
        for (int j = 0; j < 4; j++)
            acc[i][j] = (f32x4){0.f, 0.f, 0.f, 0.f};

    const int t0 = z * nt, te = t0 + nt;

    auto colA = [&](int t) {
        int k0 = t << 5;
        int seg = k0 >> KcLog, kk = k0 & (Kc - 1);
        int r3 = seg >= 3 ? seg - 3 : seg;
        int bs = seg >= 3 ? 2 : 0;
        return (bs + (r3 == 1 ? 1 : 0)) * Kc + kk;
    };
    auto colB = [&](int t) {
        int k0 = t << 5;
        int seg = k0 >> KcLog, kk = k0 & (Kc - 1);
        int r3 = seg >= 3 ? seg - 3 : seg;
        int bs = seg >= 3 ? 2 : 0;
        return (bs + (r3 == 2 ? 1 : 0)) * Kc + kk;
    };
    auto stageA = [&](int t) {
        const u16* src = A + (size_t)(m0 + srow) * K4 + colA(t) + lk8;
        char* dst = ldsA + (t & 3) * 16384 + wb;
        gload_lds16(src, dst);
        gload_lds16(src + (size_t)128 * K4, dst + 8192);
    };
    auto stageB = [&](int t) {
        const u16* src = B + (size_t)(n0 + srow) * K4 + colB(t) + lk8;
        char* dst = ldsB + (t & 3) * 16384 + wb;
        gload_lds16(src, dst);
        gload_lds16(src + (size_t)128 * K4, dst + 8192);
    };
    auto aBase = [&](int t) -> const char* {
        return ldsA + (t & 3) * 16384 + wr * 8192 + laneOff;
    };
    auto bBase = [&](int t) -> const char* {
        return ldsB + (t & 3) * 16384 + wc * 4096 + laneOff;
    };

    // prologue: stage t0, t0+1; confirm t0; read its phase-1 frags
    stageA(t0); stageB(t0);
    if (t0 + 1 < te) { stageA(t0 + 1); stageB(t0 + 1); }
    if (t0 + 1 < te) asm volatile("s_waitcnt vmcnt(4)" ::: "memory");
    else             asm volatile("s_waitcnt vmcnt(0)" ::: "memory");
    asm volatile("s_barrier" ::: "memory");

    bf16x8 b0, b1, b2, b3, a0, a1, a2, a3;
    {
        const char* aS = aBase(t0);
        const char* bS = bBase(t0);
        b0 = *(const bf16x8*)(bS + 0 * 1024);
        b1 = *(const bf16x8*)(bS + 1 * 1024);
        b2 = *(const bf16x8*)(bS + 2 * 1024);
        b3 = *(const bf16x8*)(bS + 3 * 1024);
        a0 = *(const bf16x8*)(aS + 0 * 1024);
        a1 = *(const bf16x8*)(aS + 1 * 1024);
        a2 = *(const bf16x8*)(aS + 2 * 1024);
        a3 = *(const bf16x8*)(aS + 3 * 1024);
    }

    for (int t = t0; t < te; ++t) {
        const bool haveStage = (t + 2 < te);
        const bool haveNext  = (t + 1 < te);

        // issue next-next tile's stages (loads span the whole tile)
        if (haveStage) { stageA(t + 2); stageB(t + 2); }

        // pre-read phase-2 A-frags (slot t, published) -- covered by MFMA ph1
        const char* aS = aBase(t);
        bf16x8 c0 = *(const bf16x8*)(aS + 4096 + 0 * 1024);
        bf16x8 c1 = *(const bf16x8*)(aS + 4096 + 1 * 1024);
        bf16x8 c2 = *(const bf16x8*)(aS + 4096 + 2 * 1024);
        bf16x8 c3 = *(const bf16x8*)(aS + 4096 + 3 * 1024);

        // ---- phase 1: M-half 0 ----
        __builtin_amdgcn_s_setprio(1);
        MFMA16(acc[0], acc[1], acc[2], acc[3], a0, a1, a2, a3, b0, b1, b2, b3)
        __builtin_amdgcn_s_setprio(0);

        // confirm tile t+1's 4 loads; keep t+2's 4 in flight (if staged)
        if (haveStage) asm volatile("s_waitcnt vmcnt(4)" ::: "memory");
        else           asm volatile("s_waitcnt vmcnt(0)" ::: "memory");
        asm volatile("s_barrier" ::: "memory");

        // pre-read next tile's phase-1 A-frags (a regs free after ph1)
        if (haveNext) {
            const char* aN = aBase(t + 1);
            a0 = *(const bf16x8*)(aN + 0 * 1024);
            a1 = *(const bf16x8*)(aN + 1 * 1024);
            a2 = *(const bf16x8*)(aN + 2 * 1024);
            a3 = *(const bf16x8*)(aN + 3 * 1024);
        }

        // ---- phase 2: M-half 1 ----
        __builtin_amdgcn_s_setprio(1);
        MFMA16(acc[4], acc[5], acc[6], acc[7], c0, c1, c2, c3, b0, b1, b2, b3)
        __builtin_amdgcn_s_setprio(0);

        // pre-read next tile's B-frags (b regs free after ph2)
        if (haveNext) {
            const char* bN = bBase(t + 1);
            b0 = *(const bf16x8*)(bN + 0 * 1024);
            b1 = *(const bf16x8*)(bN + 1 * 1024);
            b2 = *(const bf16x8*)(bN + 2 * 1024);
            b3 = *(const bf16x8*)(bN + 3 * 1024);
        }
    }

    // ---- epilogue ----
    const int fq = kb;
#pragma unroll
    for (int nj = 0; nj < 4; nj++) {
        int n = n0 + wc * 64 + nj * 16 + fr;
        if (EPI == 0) {
            bool left = (n < NH);
            int nn = left ? n : (n - NH);
            float bias = left ? biasL[n] : biasR[nn];
#pragma unroll
            for (int mi = 0; mi < 8; mi++) {
                int mb = m0 + wr * 128 + mi * 16 + fq * 4;
#pragma unroll
                for (int r = 0; r < 4; r++) {
                    float val = fmaxf(acc[mi][nj][r] + bias, 0.f);
                    u16 h = f2bf(val);
                    u16 lo = f2bf(val - bf2f(h));
                    size_t rb = (size_t)(mb + r) * (4 * (size_t)NH);
                    if (left) { OutU[rb + nn] = h; OutU[rb + NH + nn] = lo; }
                    else { OutU[rb + 2 * (size_t)NH + nn] = h; OutU[rb + 3 * (size_t)NH + nn] = lo; }
                }
            }
        } else {
            const size_t PSZ = (size_t)2048 * 2048;
            float* Out = (z < 2) ? (P01 + (size_t)z * PSZ) : (P23 + (size_t)(z - 2) * PSZ);
#pragma unroll
            for (int mi = 0; mi < 8; mi++) {
                int mb = m0 + wr * 128 + mi * 16 + fq * 4;
#pragma unroll
                for (int r = 0; r < 4; r++)
                    Out[(size_t)(mb + r) * 2048 + n] = acc[mi][nj][r];
            }
        }
    }
}

// ---------------------------------------------------------------------------
// Router: sum split-K partials + bias -> amp -> logits -> top-3 -> gates
// ---------------------------------------------------------------------------
__global__ __launch_bounds__(128) void router_kernel(
    const float* __restrict__ P01, const float* __restrict__ P23, int ZK,
    const float* __restrict__ b2,
    const float* __restrict__ w_gate, const float* __restrict__ w_noise,
    const float* __restrict__ noise_z, float* __restrict__ gates)
{
    __shared__ float s_amp[1024];
    __shared__ float s_logit[P_DIM];
    __shared__ int   s_idx[3];
    __shared__ float s_val[3];

    int b = blockIdx.x;
    const size_t PSZ = (size_t)2048 * 2048;
    const size_t roff = (size_t)b * 2048;

    for (int i = threadIdx.x; i < 1024; i += 128) {
        float orr = b2[i];
        float oii = b2[1024 + i];
        for (int zz = 0; zz < ZK; zz++) {
            const float* Pz = ((zz < 2) ? (P01 + (size_t)zz * PSZ)
                                        : (P23 + (size_t)(zz - 2) * PSZ)) + roff;
            orr += Pz[i];
            oii += Pz[1024 + i];
        }
        s_amp[i] = sqrtf(orr * orr + oii * oii);
    }
    __syncthreads();

    int p = threadIdx.x;
    if (p < P_DIM) {
        float cg = 0.f, cn = 0.f;
        for (int k = 0; k < 1024; k++) {
            float a = s_amp[k];
            cg = fmaf(a, w_gate[k * P_DIM + p], cg);
            cn = fmaf(a, w_noise[k * P_DIM + p], cn);
        }
        float ns = (cn > 20.f) ? cn : log1pf(expf(cn));
        ns += 0.01f;
        s_logit[p] = cg + noise_z[(size_t)b * P_DIM + p] * ns;
    }
    __syncthreads();

    if (threadIdx.x == 0) {
        int i0 = -1, i1 = -1, i2 = -1;
        float v0 = -1e30f, v1 = -1e30f, v2 = -1e30f;
        for (int i = 0; i < P_DIM; i++) {
            float t = s_logit[i];
            if (t > v0) { v0 = t; i0 = i; }
        }
        for (int i = 0; i < P_DIM; i++) {
            if (i == i0) continue;
            float t = s_logit[i];
            if (t > v1) { v1 = t; i1 = i; }
        }
        for (int i = 0; i < P_DIM; i++) {
            if (i == i0 || i == i1) continue;
            float t = s_logit[i];
            if (t > v2) { v2 = t; i2 = i; }
        }
        s_idx[0] = i0; s_idx[1] = i1; s_idx[2] = i2;
        s_val[0] = v0; s_val[1] = v1; s_val[2] = v2;
    }
    __syncthreads();

    if (p < P_DIM) {
        float m = s_val[0];
        float e0 = expf(s_val[0] - m);
        float e1 = expf(s_val[1] - m);
        float e2 = expf(s_val[2] - m);
        float inv = 1.f / (e0 + e1 + e2);
        float g = 0.f;
        if (p == s_idx[0]) g = e0 * inv;
        else if (p == s_idx[1]) g = e1 * inv;
        else if (p == s_idx[2]) g = e2 * inv;
        gates[(size_t)b * P_DIM + p] = g;
    }
}

// ---------------------------------------------------------------------------
extern "C" void kernel_launch(void* const* d_in, const int* in_sizes, int n_in,
                              void* d_out, int out_size, void* d_ws, size_t ws_size,
                              hipStream_t stream)
{
    const float* x       = (const float*)d_in[0];
    const float* w_start = (const float*)d_in[1];
    const float* b_start = (const float*)d_in[2];
    const float* w1      = (const float*)d_in[3];
    const float* b1      = (const float*)d_in[4];
    const float* w2      = (const float*)d_in[5];
    const float* b2      = (const float*)d_in[6];
    const float* w_gate  = (const float*)d_in[7];
    const float* w_noise = (const float*)d_in[8];
    const float* noise_z = (const float*)d_in[9];
    float* gates = (float*)d_out;

    const size_t MB = 1024 * 1024;
    char* base = (char*)d_ws;
    u16*  A1   = (u16*)(base + 16 * MB);     // [16,32) — dead after gemm1
    u16*  BT   = (u16*)(base + 32 * MB);     // [32,96) — BT1 then BT2
    u16*  A2   = (u16*)(base + 96 * MB);     // [96,160)
    float* P01 = (float*)base;               // partials z0,z1 -> [0,32)
    float* P23 = (float*)(base + 160 * MB);  // partials z2,z3 -> [160,192)

    int ZK = (ws_size >= (size_t)192 * MB) ? 4 : 2;

    hipFuncSetAttribute(reinterpret_cast<const void*>(&gemm8p<0, 1>),
                        hipFuncAttributeMaxDynamicSharedMemorySize, 131072);
    hipFuncSetAttribute(reinterpret_cast<const void*>(&gemm8p<1, 0>),
                        hipFuncAttributeMaxDynamicSharedMemorySize, 131072);

    fft_kernel<<<B_DIM, 256, 0, stream>>>(x, w_start, b_start, A1);

    // layer 1: M=2048, N=8192, Kc=1024 (K_eff=6144 -> 192 K32-tiles); XCD swizzle
    conv_bt_kernel<<<dim3(F_DIM / 32, H_DIM / 32), dim3(32, 8), 0, stream>>>(
        w1, BT, F_DIM, H_DIM);
    gemm8p<0, 1><<<256, 512, 131072, stream>>>(
        A1, BT, b1, b1 + H_DIM, A2, nullptr, nullptr, F_DIM, 10, H_DIM, 192);

    // layer 2: M=2048, N=2048, Kc=4096 (K_eff=24576 -> 768 K32-tiles), split-K
    conv_bt_kernel<<<dim3(H_DIM / 32, F_DIM / 32), dim3(32, 8), 0, stream>>>(
        w2, BT, H_DIM, F_DIM);
    gemm8p<1, 0><<<dim3(8, 8, ZK), 512, 131072, stream>>>(
        A2, BT, nullptr, nullptr, nullptr, P01, P23, H_DIM, 12, F_DIM, 768 / ZK);

    router_kernel<<<B_DIM, 128, 0, stream>>>(
        P01, P23, ZK, b2, w_gate, w_noise, noise_z, gates);
}